// Round 8
// baseline (123.744 us; speedup 1.0000x reference)
//
#include <hip/hip_runtime.h>
#include <hip/hip_bf16.h>
#include <math.h>

// S4D kernel — ROUND 8: MEASUREMENT ROUND. Kernel body is byte-identical to
// round 7 (dual packed 16-chains, 2 h/block, 3 ds_reads/n, 512 blocks).
// kernel_launch launches it FOUR times back-to-back (idempotent writes):
//   marginal m = (bench8 - bench7) / 3
// Discriminates: A) per-launch invariant ~13.5us (same as r6's r5-structure
// marginal despite ~2x less modeled exec work) -> dispatch/ramp/drain floor;
// B) m ~6-9us -> exec-real, r7 helped warm but single-launch masks it.

#define H_DIM 1024
#define NH 32
#define L_DIM 4096
#define TPB 256
#define NSTEP 16
#define STRIDE_F 160   // per (hh,n): 128 TA floats + 32 TB floats

typedef float v2f __attribute__((ext_vector_type(2)));

#if defined(__has_builtin) && __has_builtin(__builtin_elementwise_fma)
#define V2FMA(a, b, c) __builtin_elementwise_fma((a), (b), (c))
#else
#define V2FMA(a, b, c) ((a) * (b) + (c))
#endif

__global__ __launch_bounds__(TPB, 2) void s4d_kernel(
    const float* __restrict__ C,          // (H, NH, 2)
    const float* __restrict__ log_dt,     // (H,)
    const float* __restrict__ log_A_real, // (H, NH)
    const float* __restrict__ A_imag,     // (H, NH)
    float* __restrict__ out)              // (H, L)
{
    const int t  = threadIdx.x;
    const int hh = t >> 7;            // 0/1: which h of this block
    const int u  = t & 127;           // lane within the h-half
    const int h  = 2 * blockIdx.x + hh;

    __shared__ float lds[2 * NH * STRIDE_F];   // 40 KiB

    const double INV_2PI = 0.15915494309189533576888376337251;

    // ---------------- parallel setup: 32 n x 4 slots per h ----------------
    {
        const int n = u & 31;
        const int s = u >> 5;          // slot 0..3

        const float dtf = __expf(log_dt[h]);
        const float arf = -__expf(log_A_real[h * NH + n]); // Re(A) < 0
        const float aif = A_imag[h * NH + n];              // Im(A) >= 0
        const float are = arf * dtf;                       // Re(dtA) < 0
        const double th_rev = (double)aif * (double)dtf * INV_2PI; // revs per l

        // W = exp(dtA) (direct)
        const float mw = __expf(are);
        const float u1 = (float)(th_rev - floor(th_rev));
        const float wr = mw * __builtin_amdgcn_cosf(u1);
        const float wi = mw * __builtin_amdgcn_sinf(u1);

        // W^16 (direct)
        const float m16 = __expf(are * 16.0f);
        double u16 = th_rev * 16.0;
        u16 -= floor(u16);
        const float w16r = m16 * __builtin_amdgcn_cosf((float)u16);
        const float w16i = m16 * __builtin_amdgcn_sinf((float)u16);

        // cm = 2 * Cc * (W - 1) / A
        const float cr = C[(h * NH + n) * 2 + 0];
        const float ci = C[(h * NH + n) * 2 + 1];
        const float er = wr - 1.0f;
        const float ei = wi;
        const float tr = cr * er - ci * ei;
        const float ti = cr * ei + ci * er;
        const float inv = 2.0f / (arf * arf + aif * aif);
        const float cmr = (tr * arf + ti * aif) * inv;
        const float cmi = (ti * arf - tr * aif) * inv;

        const float p = wr + wr;              // 2 Re(W)
        const float q = -__expf(are + are);   // -|W|^2

        float* base = &lds[(hh * NH + n) * STRIDE_F];

        // TA[i], i = s + 4k (k=0..3): {cm*W^(32i), cm*W^(32i+1),
        //                              cm*W^(32i+16), cm*W^(32i+17)}
#pragma unroll
        for (int k = 0; k < 4; ++k) {
            const int i = s + 4 * k;
            const int l = 32 * i;
            const float mag = __expf(are * (float)l);
            double uu = (double)l * th_rev;
            uu -= floor(uu);
            const float pr = mag * __builtin_amdgcn_cosf((float)uu);
            const float pi = mag * __builtin_amdgcn_sinf((float)uu);
            const float e0r = cmr * pr - cmi * pi;
            const float e0i = cmr * pi + cmi * pr;
            const float e1r = e0r * wr - e0i * wi;
            const float e1i = e0r * wi + e0i * wr;
            const float f0r = e0r * w16r - e0i * w16i;
            const float f0i = e0r * w16i + e0i * w16r;
            const float f1r = f0r * wr - f0i * wi;
            const float f1i = f0r * wi + f0i * wr;
            float* p8 = base + 8 * i;
            p8[0] = e0r; p8[1] = e0i; p8[2] = e1r; p8[3] = e1i;
            p8[4] = f0r; p8[5] = f0i; p8[6] = f1r; p8[7] = f1i;
        }
        // TB[b], b = s + 4k (k=0..1): {W^(512b), p, q}
#pragma unroll
        for (int k = 0; k < 2; ++k) {
            const int b = s + 4 * k;
            const int l = 512 * b;
            const float mag = __expf(are * (float)l);
            double uu = (double)l * th_rev;
            uu -= floor(uu);
            float* p4 = base + 128 + 4 * b;
            p4[0] = mag * __builtin_amdgcn_cosf((float)uu);
            p4[1] = mag * __builtin_amdgcn_sinf((float)uu);
            p4[2] = p;
            p4[3] = q;
        }
    }
    __syncthreads();

    // ---------------- main loop: dual packed 16-chains, 32 l/thread -------
    v2f acc[NSTEP];
#pragma unroll
    for (int j = 0; j < NSTEP; ++j) acc[j] = (v2f){0.0f, 0.0f};

    const int a = u & 15;   // TA index  (l0 = 32u = 32a + 512b)
    const int b = u >> 4;   // TB index

    const float* hbase = &lds[hh * NH * STRIDE_F];

#pragma unroll 2
    for (int n = 0; n < NH; ++n) {
        const float* base = hbase + n * STRIDE_F;
        const float4 ta0 = *(const float4*)(base + 8 * a);       // e0, e1
        const float4 ta1 = *(const float4*)(base + 8 * a + 4);   // e16, e17
        const float4 tb  = *(const float4*)(base + 128 + 4 * b); // T, p, q

        const float x0A = ta0.x * tb.x - ta0.y * tb.y;
        const float x1A = ta0.z * tb.x - ta0.w * tb.y;
        const float x0B = ta1.x * tb.x - ta1.y * tb.y;
        const float x1B = ta1.z * tb.x - ta1.w * tb.y;

        v2f x1 = {x1A, x1B};
        const v2f x0 = {x0A, x0B};
        const v2f p2 = {tb.z, tb.z};
        const v2f q2 = {tb.w, tb.w};

        acc[0] += x0;
        acc[1] += x1;
        v2f tq = q2 * x0;
#pragma unroll
        for (int j = 2; j < NSTEP; ++j) {
            const v2f x2 = V2FMA(p2, x1, tq);
            tq = q2 * x1;                    // off critical path
            acc[j] += x2;
            x1 = x2;
        }
    }

    float4* op = (float4*)(out + (size_t)h * L_DIM + 32 * u);
#pragma unroll
    for (int k = 0; k < 4; ++k) {
        op[k]     = make_float4(acc[4 * k].x, acc[4 * k + 1].x,
                                acc[4 * k + 2].x, acc[4 * k + 3].x);
        op[4 + k] = make_float4(acc[4 * k].y, acc[4 * k + 1].y,
                                acc[4 * k + 2].y, acc[4 * k + 3].y);
    }
}

extern "C" void kernel_launch(void* const* d_in, const int* in_sizes, int n_in,
                              void* d_out, int out_size, void* d_ws, size_t ws_size,
                              hipStream_t stream) {
    const float* C          = (const float*)d_in[0];
    const float* log_dt     = (const float*)d_in[1];
    const float* log_A_real = (const float*)d_in[2];
    const float* A_imag     = (const float*)d_in[3];
    float* out = (float*)d_out;

    // MEASUREMENT: 4 identical idempotent launches.
    // marginal m = (bench - 78.1us) / 3 ; A: m~13.5 -> per-launch floor,
    // B: m~6-9 -> exec-real. Round 9 reverts to single launch.
    for (int rep = 0; rep < 4; ++rep) {
        s4d_kernel<<<dim3(H_DIM / 2), dim3(TPB), 0, stream>>>(C, log_dt, log_A_real, A_imag, out);
    }
}

// Round 9
// 75.821 us; speedup vs baseline: 1.6321x; 1.6321x over previous
//
#include <hip/hip_runtime.h>
#include <hip/hip_bf16.h>
#include <math.h>

// S4D kernel: K[h,l] = 2 * Re( sum_n Cm[h,n] * W[h,n]^l ),  W = exp(dtA)
//   dtA = dt * (-exp(log_A_real) + i*A_imag),  dt = exp(log_dt)
//   Cm  = Cc * (exp(dtA) - 1) / A
// H=1024, NH=N/2=32, L=4096. Output (H, L) float32.
//
// FINAL (round 9 = round 5 kernel, single launch — best measured: 77.9 us
// bench; kernel exec ~4 us + ~10 us per-launch floor + ~64 us harness fixed).
// Measurement rounds r6/r8 showed per-launch marginal ~14 us invariant under
// 2x changes in occupancy / issue count / DS traffic / chain depth ->
// single-launch structure is at its floor.
//
//  - Thread t owns l in [16t, 16t+16) as TWO 8-chains (A: +0..7, B: +8..15)
//    advanced in lockstep as float2 -> v_pk_fma_f32 / v_pk_mul_f32.
//  - seed_B = seed_A * W^8 (W^8 per n in LDS header).
//  - 2nd-order real recurrence x_{j+1} = p*x_j + q*x_{j-1},
//    p = 2Re(W), q = -exp(2 Re(dtA)).
//  - Setup fully parallel (32 n x 8 slots), HW v_sin/v_cos on
//    frac-of-revolutions (f64 reduction), no libm, no serial chains.

#define H_DIM 1024
#define NH 32
#define L_DIM 4096
#define TPB 256
#define CHUNK 8
#define STRIDE_F 72   // 4 hdr + 2 w8 + 32 TA + 32 TB floats (288 B)

typedef float v2f __attribute__((ext_vector_type(2)));

#if defined(__has_builtin) && __has_builtin(__builtin_elementwise_fma)
#define V2FMA(a, b, c) __builtin_elementwise_fma((a), (b), (c))
#else
#define V2FMA(a, b, c) ((a) * (b) + (c))
#endif

__global__ __launch_bounds__(TPB, 4) void s4d_kernel(
    const float* __restrict__ C,          // (H, NH, 2)
    const float* __restrict__ log_dt,     // (H,)
    const float* __restrict__ log_A_real, // (H, NH)
    const float* __restrict__ A_imag,     // (H, NH)
    float* __restrict__ out)              // (H, L)
{
    const int h = blockIdx.x;
    const int t = threadIdx.x;

    __shared__ float lds[NH * STRIDE_F];

    const double INV_2PI = 0.15915494309189533576888376337251;

    // ---------------- parallel setup ----------------
    {
        const int n = t & 31;
        const int s = t >> 5;   // slot 0..7

        const float dtf = __expf(log_dt[h]);
        const float arf = -__expf(log_A_real[h * NH + n]); // Re(A) < 0
        const float aif = A_imag[h * NH + n];              // Im(A) >= 0
        const float are = arf * dtf;                       // Re(dtA) < 0
        const double th_rev = (double)aif * (double)dtf * INV_2PI; // revs per l

        // W = exp(dtA)
        const float mw = __expf(are);
        const float u1 = (float)(th_rev - floor(th_rev));
        const float wr = mw * __builtin_amdgcn_cosf(u1);
        const float wi = mw * __builtin_amdgcn_sinf(u1);

        // cm = 2 * Cc * (W - 1) / A   (redundant per slot)
        const float cr = C[(h * NH + n) * 2 + 0];
        const float ci = C[(h * NH + n) * 2 + 1];
        const float er = wr - 1.0f;
        const float ei = wi;
        const float tr = cr * er - ci * ei;
        const float ti = cr * ei + ci * er;
        const float inv = 2.0f / (arf * arf + aif * aif);
        const float cmr = (tr * arf + ti * aif) * inv;
        const float cmi = (ti * arf - tr * aif) * inv;

        float* base = &lds[n * STRIDE_F];

        // TA[i] = cm * W^(16i), i in [0,16): slot fills i = s, s+8
#pragma unroll
        for (int k = 0; k < 2; ++k) {
            const int i = s + 8 * k;
            const int l = 16 * i;
            const float mag = __expf(are * (float)l);
            double u = (double)l * th_rev;
            u -= floor(u);
            const float uf = (float)u;
            const float br = mag * __builtin_amdgcn_cosf(uf);
            const float bi = mag * __builtin_amdgcn_sinf(uf);
            base[6 + 2 * i]     = cmr * br - cmi * bi;
            base[6 + 2 * i + 1] = cmr * bi + cmi * br;
        }
        // TB[i] = W^(256i), i in [0,16): slot fills i = s, s+8
#pragma unroll
        for (int k = 0; k < 2; ++k) {
            const int i = s + 8 * k;
            const int l = 256 * i;
            const float mag = __expf(are * (float)l);
            double u = (double)l * th_rev;
            u -= floor(u);
            const float uf = (float)u;
            base[38 + 2 * i]     = mag * __builtin_amdgcn_cosf(uf);
            base[38 + 2 * i + 1] = mag * __builtin_amdgcn_sinf(uf);
        }
        if (s == 0) {
            base[0] = wr;
            base[1] = wi;
            base[2] = wr + wr;             // p = 2 Re(W)
            base[3] = -__expf(are + are);  // q = -|W|^2
            // W^8 (direct, accurate)
            const float m8 = __expf(are * 8.0f);
            double u8 = th_rev * 8.0;
            u8 -= floor(u8);
            const float uf8 = (float)u8;
            base[4] = m8 * __builtin_amdgcn_cosf(uf8);
            base[5] = m8 * __builtin_amdgcn_sinf(uf8);
        }
    }
    __syncthreads();

    // ---------------- main loop: packed dual 8-chains ----------------
    v2f acc[CHUNK];
#pragma unroll
    for (int j = 0; j < CHUNK; ++j) acc[j] = (v2f){0.0f, 0.0f};

    const int ia = t & 15;   // TA index
    const int ib = t >> 4;   // TB index

#pragma unroll 4
    for (int n = 0; n < NH; ++n) {
        const float* base = &lds[n * STRIDE_F];
        const float4 h4 = *(const float4*)base;                  // wr wi p q
        const float2 w8 = *(const float2*)(base + 4);            // W^8
        const float2 ta = *(const float2*)(base + 6 + 2 * ia);
        const float2 tb = *(const float2*)(base + 38 + 2 * ib);

        // chain A seed: zA = TA[ia]*TB[ib] = cm * W^(16t)
        const float zr  = ta.x * tb.x - ta.y * tb.y;
        const float zi  = ta.x * tb.y + ta.y * tb.x;
        // chain B seed: zB = zA * W^8
        const float zbr = zr * w8.x - zi * w8.y;
        const float zbi = zr * w8.y + zi * w8.x;

        v2f x0 = {zr, zbr};
        v2f x1 = {zr * h4.x - zi * h4.y, zbr * h4.x - zbi * h4.y};
        acc[0] += x0;
        acc[1] += x1;
        const v2f p2 = {h4.z, h4.z};
        const v2f q2 = {h4.w, h4.w};
        v2f tq = q2 * x0;
#pragma unroll
        for (int j = 2; j < CHUNK; ++j) {
            const v2f x2 = V2FMA(p2, x1, tq);
            tq = q2 * x1;                    // off critical path
            acc[j] += x2;
            x1 = x2;
        }
    }

    float4* op = (float4*)(out + (size_t)h * L_DIM + t * 16);
    op[0] = make_float4(acc[0].x, acc[1].x, acc[2].x, acc[3].x);
    op[1] = make_float4(acc[4].x, acc[5].x, acc[6].x, acc[7].x);
    op[2] = make_float4(acc[0].y, acc[1].y, acc[2].y, acc[3].y);
    op[3] = make_float4(acc[4].y, acc[5].y, acc[6].y, acc[7].y);
}

extern "C" void kernel_launch(void* const* d_in, const int* in_sizes, int n_in,
                              void* d_out, int out_size, void* d_ws, size_t ws_size,
                              hipStream_t stream) {
    const float* C          = (const float*)d_in[0];
    const float* log_dt     = (const float*)d_in[1];
    const float* log_A_real = (const float*)d_in[2];
    const float* A_imag     = (const float*)d_in[3];
    float* out = (float*)d_out;

    s4d_kernel<<<dim3(H_DIM), dim3(TPB), 0, stream>>>(C, log_dt, log_A_real, A_imag, out);
}